// Round 2
// baseline (9956.467 us; speedup 1.0000x reference)
//
#include <hip/hip_runtime.h>
#include <cstdio>

constexpr int B_ = 32, L_ = 1024, C_ = 512;

// Static device workspace: 112,800,000 floats = 451.2 MB, zero-init BSS,
// allocated at module load (harness-legal; d_ws size is unknown/unreliable).
constexpr size_t WS_N = 112800000;
__device__ float g_ws[WS_N];

// ---------------------------------------------------------------- decomp ----
// res = src - moving_avg(src, DK)  (replicate pad), src/res: [B, L, C]
template<int DK>
__global__ __launch_bounds__(256) void decomp_k(const float* __restrict__ src,
                                                float* __restrict__ res) {
  constexpr int P = (DK - 1) / 2;
  constexpr int ROWS = 64 + DK - 1;
  __shared__ float buf[ROWS][128];
  int b = blockIdx.y;
  int l0 = blockIdx.x * 64;
  int c0 = blockIdx.z * 128;
  for (int i = threadIdx.x; i < ROWS * 128; i += 256) {
    int rr = i >> 7, cc = i & 127;
    int ll = l0 - P + rr;
    ll = ll < 0 ? 0 : (ll > L_ - 1 ? L_ - 1 : ll);
    buf[rr][cc] = src[((long)b * L_ + ll) * C_ + c0 + cc];
  }
  __syncthreads();
  for (int i = threadIdx.x; i < 64 * 128; i += 256) {
    int rr = i >> 7, cc = i & 127;
    float s = 0.f;
#pragma unroll
    for (int j = 0; j < DK; ++j) s += buf[rr + j][cc];
    res[((long)b * L_ + l0 + rr) * C_ + c0 + cc] = buf[rr + P][cc] - s * (1.0f / DK);
  }
}

// --------------------------------------------------------------- im2col -----
// im[(b*2+par)*Lc + t][ci*KC + tau] = res[b][2*(t*KC - PAD + tau) + par][ci] (0 OOB)
template<int KC>
__global__ __launch_bounds__(256) void im2col_down_k(const float* __restrict__ res,
                                                     float* __restrict__ im, int Lc) {
  constexpr int PAD = KC / 2;
  __shared__ float lds[KC][C_ + 1];
  int row = blockIdx.x;
  int t = row % Lc, bp = row / Lc;
  int par = bp & 1, b = bp >> 1;
  for (int i = threadIdx.x; i < KC * C_; i += 256) {
    int tau = i / C_, ci = i & (C_ - 1);
    int j = t * KC - PAD + tau;
    float v = 0.f;
    if (j >= 0 && j < L_ / 2) v = res[((long)b * L_ + 2 * j + par) * C_ + ci];
    lds[tau][ci] = v;
  }
  __syncthreads();
  long base = (long)row * (C_ * KC);
  for (int i = threadIdx.x; i < C_ * KC; i += 256) {
    im[base + i] = lds[i % KC][i / KC];
  }
}

// ------------------------------------------------------------- transpose ----
// in [R][Cc] row-major -> out [Cc][R]
__global__ __launch_bounds__(256) void transpose_k(const float* __restrict__ in,
                                                   float* __restrict__ out, int R, int Cc) {
  __shared__ float t[32][33];
  int c0 = blockIdx.x * 32, r0 = blockIdx.y * 32;
  int tx = threadIdx.x & 31, ty = threadIdx.x >> 5;
  for (int i = ty; i < 32; i += 8) {
    int r = r0 + i, c = c0 + tx;
    t[i][tx] = (r < R && c < Cc) ? in[(long)r * Cc + c] : 0.f;
  }
  __syncthreads();
  for (int i = ty; i < 32; i += 8) {
    int c = c0 + i, r = r0 + tx;
    if (c < Cc && r < R) out[(long)c * R + r] = t[tx][i];
  }
}

// twr[c][j*C + o] = tw[c][o][j]   (tw: [C][C][KC])
template<int KC>
__global__ __launch_bounds__(256) void make_twr_k(const float* __restrict__ tw,
                                                  float* __restrict__ twr) {
  __shared__ float buf[KC * C_];
  int c = blockIdx.x;
  const float* ip = tw + (long)c * C_ * KC;
  for (int i = threadIdx.x; i < C_ * KC; i += 256) buf[i] = ip[i];
  __syncthreads();
  float* op = twr + (long)c * C_ * KC;
  for (int i = threadIdx.x; i < C_ * KC; i += 256) {
    int j = i >> 9, o = i & 511;
    op[i] = buf[o * KC + j];
  }
}

// mwt[(n*C + c)][o] = mw[o][c][n]   (mw: [C][C][2][1])
__global__ void make_mwt_k(const float* __restrict__ mw, float* __restrict__ mwt) {
  int idx = blockIdx.x * 256 + threadIdx.x;
  if (idx >= 1024 * C_) return;
  int o = idx & 511, kk = idx >> 9;
  int c = kk & 511, n = kk >> 9;
  mwt[idx] = mw[((long)o * C_ + c) * 2 + n];
}

// ctab[s][u] = cos(2*pi*u*(s+m-1)/N) ; itab[t][s] = cos(2*pi*t*s/m)/m
__global__ void costab_k(float* __restrict__ ctab, float* __restrict__ itab, int m, int N) {
  int idx = blockIdx.x * 256 + threadIdx.x;
  int tot = m * N;
  const double TWO_PI = 6.283185307179586476925286766559;
  if (idx < tot) {
    int s = idx / N, u = idx % N;
    int r = (int)(((long)u * (s + m - 1)) % N);
    ctab[idx] = (float)cos((double)r * (TWO_PI / N));
  } else if (idx < tot + m * m) {
    int j = idx - tot;
    int tt = j / m, s = j % m;
    int r = (tt * s) % m;
    itab[j] = (float)(cos((double)r * (TWO_PI / m)) / m);
  }
}

// ------------------------------------------------------------- interleave ---
// x1[r][2t] = xo*exp(xe); x1[r][2t+1] = xe*exp(xo) (last odd dropped); r = b*C+c
__global__ __launch_bounds__(256) void interleave_k(const float* __restrict__ xeo,
                                                    float* __restrict__ x1, int Lc, int m) {
  int idx = blockIdx.x * 256 + threadIdx.x;
  if (idx >= B_ * C_ * Lc) return;
  int t = idx % Lc, r = idx / Lc;
  float e = xeo[(long)r * (2 * Lc) + t];
  float o = xeo[(long)r * (2 * Lc) + Lc + t];
  long base = (long)r * m;
  x1[base + 2 * t] = o * expf(e);
  if (2 * t + 1 < m) x1[base + 2 * t + 1] = e * expf(o);
}

// ------------------------------------------------------------------ GEMM ----
constexpr int AM_PLAIN = 0, AM_ISO = 1;
constexpr int ACT_NONE = 0, ACT_TANH = 1, ACT_RELU = 2;

// out[bz*Obs + row*ors + col*ocs] = act(acc + bias) (+ addb[...])
// A (PLAIN): Ab[row*lda + k]; (ISO): Ab[(k/PM)*PN + k%PM + row]  (Hankel gather)
// Bm is always [K][N] row-major, shared across batches.
template<int AMODE, int ACT, bool ADD, bool BIAS, bool BIASMOD, int PM, int PN>
__global__ __launch_bounds__(256) void gemm_k(
    const float* __restrict__ A, const float* __restrict__ Bm,
    const float* __restrict__ bias, const float* __restrict__ addb,
    float* __restrict__ out, int M, int N, int K,
    long Abs, int lda, long Obs, long ors, long ocs,
    long Adbs, long adr, long adc) {
  __shared__ float As[16][68];
  __shared__ float Bs[16][64];
  int m0 = blockIdx.y * 64, n0 = blockIdx.x * 64;
  int tid = threadIdx.x;
  int tx = tid & 15, ty = tid >> 4;
  const float* Ab = A + (long)blockIdx.z * Abs;

  float acc[4][4] = {};
  float pa[4], pb[4];

  auto loadA = [&](int k0) {
#pragma unroll
    for (int i = 0; i < 4; ++i) {
      int e = i * 256 + tid;
      int row = e >> 4, kk = e & 15;
      int gr = m0 + row, gk = k0 + kk;
      float v = 0.f;
      if (gr < M && gk < K) {
        if constexpr (AMODE == AM_ISO) {
          int ci = gk / PM, tau = gk % PM;
          v = Ab[(long)ci * PN + tau + gr];
        } else {
          v = Ab[(long)gr * lda + gk];
        }
      }
      pa[i] = v;
    }
  };
  auto loadB = [&](int k0) {
#pragma unroll
    for (int i = 0; i < 4; ++i) {
      int e = i * 256 + tid;
      int kk = e >> 6, n = e & 63;
      int gk = k0 + kk, gn = n0 + n;
      pb[i] = (gk < K && gn < N) ? Bm[(long)gk * N + gn] : 0.f;
    }
  };

  loadA(0);
  loadB(0);
  int nk = (K + 15) >> 4;
  for (int kt = 0; kt < nk; ++kt) {
#pragma unroll
    for (int i = 0; i < 4; ++i) {
      int e = i * 256 + tid;
      As[e & 15][e >> 4] = pa[i];
    }
#pragma unroll
    for (int i = 0; i < 4; ++i) {
      int e = i * 256 + tid;
      Bs[e >> 6][e & 63] = pb[i];
    }
    __syncthreads();
    if (kt + 1 < nk) { loadA((kt + 1) * 16); loadB((kt + 1) * 16); }
#pragma unroll
    for (int kk = 0; kk < 16; ++kk) {
      float4 av = *(const float4*)&As[kk][ty * 4];
      float4 bv = *(const float4*)&Bs[kk][tx * 4];
      float ar[4] = {av.x, av.y, av.z, av.w};
      float br[4] = {bv.x, bv.y, bv.z, bv.w};
#pragma unroll
      for (int i2 = 0; i2 < 4; ++i2)
#pragma unroll
        for (int j2 = 0; j2 < 4; ++j2)
          acc[i2][j2] = fmaf(ar[i2], br[j2], acc[i2][j2]);
    }
    __syncthreads();
  }

#pragma unroll
  for (int i = 0; i < 4; ++i) {
    int gr = m0 + ty * 4 + i;
    if (gr >= M) continue;
#pragma unroll
    for (int j = 0; j < 4; ++j) {
      int gc = n0 + tx * 4 + j;
      if (gc >= N) continue;
      float v = acc[i][j];
      if constexpr (BIAS) v += bias[BIASMOD ? (gc & (C_ - 1)) : gc];
      if constexpr (ACT == ACT_TANH) v = tanhf(v);
      else if constexpr (ACT == ACT_RELU) v = fmaxf(v, 0.f);
      if constexpr (ADD) v += addb[(long)blockIdx.z * Adbs + (long)gr * adr + (long)gc * adc];
      out[(long)blockIdx.z * Obs + (long)gr * ors + (long)gc * ocs] = v;
    }
  }
}

// --------------------------------------------------------------- layernorm --
__global__ __launch_bounds__(256) void ln_rows_k(const float* __restrict__ in,
    const float* __restrict__ g, const float* __restrict__ be,
    float* __restrict__ out, long irs, long ors_, long ooff) {
  long row = blockIdx.x;
  const float* ip = in + row * irs;
  int t = threadIdx.x;
  float v0 = ip[t], v1 = ip[t + 256];
  float s1 = v0 + v1, s2 = v0 * v0 + v1 * v1;
#pragma unroll
  for (int o = 32; o > 0; o >>= 1) {
    s1 += __shfl_down(s1, o);
    s2 += __shfl_down(s2, o);
  }
  __shared__ float a1[4], a2[4];
  if ((t & 63) == 0) { a1[t >> 6] = s1; a2[t >> 6] = s2; }
  __syncthreads();
  float S1 = a1[0] + a1[1] + a1[2] + a1[3];
  float S2 = a2[0] + a2[1] + a2[2] + a2[3];
  float mu = S1 * (1.0f / C_);
  float var = S2 * (1.0f / C_) - mu * mu;
  float rstd = rsqrtf(var + 1e-5f);
  float* op = out + row * ors_ + ooff;
  op[t] = (v0 - mu) * rstd * g[t] + be[t];
  op[t + 256] = (v1 - mu) * rstd * g[t + 256] + be[t + 256];
}

// nearest-interp + residual + LN; writes into outcat[:, :, coloff:coloff+512]
__global__ __launch_bounds__(256) void interp_add_ln_k(
    const float* __restrict__ yct, const float* __restrict__ res,
    const float* __restrict__ g, const float* __restrict__ be,
    float* __restrict__ outcat, int Lk, int coloff) {
  int bl = blockIdx.x;
  int b = bl >> 10, l = bl & 1023;
  int pos = (int)(((long)l * Lk) >> 10);
  const float* yp = yct + ((long)b * Lk + pos) * C_;
  const float* rp = res + (long)bl * C_;
  int t = threadIdx.x;
  float v0 = yp[t] + rp[t];
  float v1 = yp[t + 256] + rp[t + 256];
  float s1 = v0 + v1, s2 = v0 * v0 + v1 * v1;
#pragma unroll
  for (int o = 32; o > 0; o >>= 1) {
    s1 += __shfl_down(s1, o);
    s2 += __shfl_down(s2, o);
  }
  __shared__ float a1[4], a2[4];
  if ((t & 63) == 0) { a1[t >> 6] = s1; a2[t >> 6] = s2; }
  __syncthreads();
  float S1 = a1[0] + a1[1] + a1[2] + a1[3];
  float S2 = a2[0] + a2[1] + a2[2] + a2[3];
  float mu = S1 * (1.0f / C_);
  float var = S2 * (1.0f / C_) - mu * mu;
  float rstd = rsqrtf(var + 1e-5f);
  float* op = outcat + (long)bl * 1024 + coloff;
  op[t] = (v0 - mu) * rstd * g[t] + be[t];
  op[t + 256] = (v1 - mu) * rstd * g[t + 256] + be[t + 256];
}

// ================================================================= launch ===
extern "C" void kernel_launch(void* const* d_in, const int* in_sizes, int n_in,
                              void* d_out, int out_size, void* d_ws, size_t ws_size,
                              hipStream_t stream) {
  (void)in_sizes; (void)n_in; (void)out_size; (void)d_ws; (void)ws_size;
  const float* src = (const float*)d_in[0];
  const float* cw[2] = {(const float*)d_in[1], (const float*)d_in[7]};
  const float* cb[2] = {(const float*)d_in[2], (const float*)d_in[8]};
  const float* iw[2] = {(const float*)d_in[3], (const float*)d_in[9]};
  const float* ib[2] = {(const float*)d_in[4], (const float*)d_in[10]};
  const float* tw[2] = {(const float*)d_in[5], (const float*)d_in[11]};
  const float* tb[2] = {(const float*)d_in[6], (const float*)d_in[12]};
  const float* mw  = (const float*)d_in[13];
  const float* mb  = (const float*)d_in[14];
  const float* ng  = (const float*)d_in[15];
  const float* nb  = (const float*)d_in[16];
  const float* fw1 = (const float*)d_in[17];
  const float* fb1 = (const float*)d_in[18];
  const float* fw2 = (const float*)d_in[19];
  const float* fb2 = (const float*)d_in[20];
  const float* fng = (const float*)d_in[21];
  const float* fnb = (const float*)d_in[22];
  float* outp = (float*)d_out;

  // Resolve the static device workspace once (first call is the uncaptured
  // correctness call; graph capture then sees zero extra API calls).
  static float* ws = [] {
    void* p = nullptr;
    hipGetSymbolAddress(&p, HIP_SYMBOL(g_ws));
    return (float*)p;
  }();

  size_t off = 0;
  auto alloc = [&](size_t n) { float* p = ws + off; off += n; return p; };
  float* res    = alloc((size_t)B_ * L_ * C_);        // 16.78M floats
  float* big    = alloc((size_t)17301504);            // im2col | yct | FFN-hidden
  float* xeo    = alloc((size_t)B_ * C_ * 86);
  float* x1     = alloc((size_t)B_ * C_ * 85);
  float* xf     = alloc((size_t)B_ * C_ * 169);
  float* xi     = alloc((size_t)B_ * C_ * 85);
  float* zz     = alloc((size_t)B_ * 85 * C_);
  float* yy     = alloc((size_t)B_ * 85 * C_);
  float* outcat = alloc((size_t)B_ * L_ * 1024);      // 33.55M
  float* witmg  = alloc((size_t)43520 * 512);         // iso-W^T | merge output mg
  float* wdt    = alloc((size_t)12288 * 512);
  float* twr    = alloc((size_t)512 * 24 * 512);
  float* mwt    = alloc((size_t)1024 * 512);
  float* ctab   = alloc((size_t)85 * 169);
  float* itab   = alloc((size_t)85 * 85);
  float* mg   = witmg;   // reuse: wit dead after branches
  float* hid  = big;     // reuse: yct dead after branches
  float* spre = res;     // reuse: res dead after branches

  const int Ks[2] = {12, 24}, Ms[2] = {85, 43};

  for (int br = 0; br < 2; ++br) {
    const int KC = Ks[br], m = Ms[br], Lc = (m + 1) / 2, N2 = 2 * m - 1;
    const int Lk = m * KC, KK = C_ * KC;

    if (br == 0) decomp_k<17><<<dim3(L_ / 64, B_, 4), 256, 0, stream>>>(src, res);
    else         decomp_k<33><<<dim3(L_ / 64, B_, 4), 256, 0, stream>>>(src, res);

    if (br == 0) im2col_down_k<12><<<B_ * 2 * Lc, 256, 0, stream>>>(res, big, Lc);
    else         im2col_down_k<24><<<B_ * 2 * Lc, 256, 0, stream>>>(res, big, Lc);

    transpose_k<<<dim3(KK / 32, C_ / 32), 256, 0, stream>>>(cw[br], wdt, C_, KK);

    // down conv (even|odd stacked rows) + bias + tanh -> xeo [B][C][2Lc]
    gemm_k<AM_PLAIN, ACT_TANH, false, true, false, 0, 0>
        <<<dim3(C_ / 64, (2 * Lc + 63) / 64, B_), 256, 0, stream>>>(
            big, wdt, cb[br], nullptr, xeo, 2 * Lc, C_, KK,
            (long)2 * Lc * KK, KK, (long)C_ * 2 * Lc, 1, 2 * Lc, 0, 0, 0);

    {
      int tot = B_ * C_ * Lc;
      interleave_k<<<(tot + 255) / 256, 256, 0, stream>>>(xeo, x1, Lc, m);
    }
    {
      int tot = m * N2 + m * m;
      costab_k<<<(tot + 255) / 256, 256, 0, stream>>>(ctab, itab, m, N2);
    }

    // Re(FFT): xf[bc][u] = sum_s x1[bc][s] * ctab[s][u]
    gemm_k<AM_PLAIN, ACT_NONE, false, false, false, 0, 0>
        <<<dim3((N2 + 63) / 64, (B_ * C_) / 64, 1), 256, 0, stream>>>(
            x1, ctab, nullptr, nullptr, xf, B_ * C_, N2, m,
            0, m, 0, N2, 1, 0, 0, 0);

    transpose_k<<<dim3((C_ * m) / 32, C_ / 32), 256, 0, stream>>>(iw[br], witmg, C_, C_ * m);

    // isometric conv (Hankel gather over xf) + bias + tanh -> xi [B][C][m]
    if (br == 0)
      gemm_k<AM_ISO, ACT_TANH, false, true, false, 85, 169>
          <<<dim3(C_ / 64, (m + 63) / 64, B_), 256, 0, stream>>>(
              xf, witmg, ib[br], nullptr, xi, m, C_, C_ * m,
              (long)C_ * N2, 0, (long)C_ * m, 1, m, 0, 0, 0);
    else
      gemm_k<AM_ISO, ACT_TANH, false, true, false, 43, 85>
          <<<dim3(C_ / 64, (m + 63) / 64, B_), 256, 0, stream>>>(
              xf, witmg, ib[br], nullptr, xi, m, C_, C_ * m,
              (long)C_ * N2, 0, (long)C_ * m, 1, m, 0, 0, 0);

    // Re(IFFT) + x1 -> zz [B][m][C]
    gemm_k<AM_PLAIN, ACT_NONE, true, false, false, 0, 0>
        <<<dim3((m + 63) / 64, C_ / 64, B_), 256, 0, stream>>>(
            xi, itab, nullptr, x1, zz, C_, m, m,
            (long)C_ * m, m, (long)m * C_, 1, C_, (long)C_ * m, m, 1);

    ln_rows_k<<<B_ * m, 256, 0, stream>>>(zz, ng, nb, yy, C_, C_, 0);

    if (br == 0) make_twr_k<12><<<C_, 256, 0, stream>>>(tw[br], twr);
    else         make_twr_k<24><<<C_, 256, 0, stream>>>(tw[br], twr);

    // conv-transpose + bias + tanh -> yct [B][Lk][C]  (in `big`)
    gemm_k<AM_PLAIN, ACT_TANH, false, true, true, 0, 0>
        <<<dim3((KC * C_) / 64, (m + 63) / 64, B_), 256, 0, stream>>>(
            yy, twr, tb[br], nullptr, big, m, KC * C_, C_,
            (long)m * C_, C_, (long)Lk * C_, (long)KC * C_, 1, 0, 0, 0);

    interp_add_ln_k<<<B_ * L_, 256, 0, stream>>>(big, res, ng, nb, outcat, Lk, br * 512);
  }

  // merge conv2d (N,1) == GEMM over concat(out0,out1)
  make_mwt_k<<<(1024 * C_ + 255) / 256, 256, 0, stream>>>(mw, mwt);
  gemm_k<AM_PLAIN, ACT_NONE, false, true, false, 0, 0>
      <<<dim3(C_ / 64, (B_ * L_) / 64, 1), 256, 0, stream>>>(
          outcat, mwt, mb, nullptr, mg, B_ * L_, C_, 1024,
          0, 1024, 0, C_, 1, 0, 0, 0);

  // FFN (chunked hidden to bound ws): relu(mg@W1+b1)@W2+b2 + mg -> spre
  for (int c0 = 0; c0 < B_ * L_; c0 += 8192) {
    gemm_k<AM_PLAIN, ACT_RELU, false, true, false, 0, 0>
        <<<dim3(2048 / 64, 8192 / 64, 1), 256, 0, stream>>>(
            mg + (size_t)c0 * C_, fw1, fb1, nullptr, hid, 8192, 2048, C_,
            0, C_, 0, 2048, 1, 0, 0, 0);
    gemm_k<AM_PLAIN, ACT_NONE, true, true, false, 0, 0>
        <<<dim3(C_ / 64, 8192 / 64, 1), 256, 0, stream>>>(
            hid, fw2, fb2, mg + (size_t)c0 * C_, spre + (size_t)c0 * C_, 8192, C_, 2048,
            0, 2048, 0, C_, 1, 0, C_, 1);
  }

  ln_rows_k<<<B_ * L_, 256, 0, stream>>>(spre, fng, fnb, outp, C_, C_, 0);
}